// Round 4
// baseline (564.094 us; speedup 1.0000x reference)
//
#include <hip/hip_runtime.h>

#define BB 16
#define ENC 64
#define HH 96
#define EE 128
#define VV 32000
#define EP 192   // padded enc row: 47 left + 96 real + 48 right = 191, alloc 192

// ---------------------------------------------------------------------------
// K0: enc_feat[b,o,x] = sum_{i,kw} attn_w[o,i,47,kw] * encpad[b,i,x+kw]
// (conv kh collapses to kh=47: input spatial height 1, pad (47,48))
// grid 512 = 16 b * 32 o-groups (o-tile 2), 128 threads (x = 0..95)
// ---------------------------------------------------------------------------
__global__ __launch_bounds__(128) void k_encfeat(
    const float* __restrict__ enc,      // (B,ENC,H) fp32
    const float* __restrict__ attn_w,   // (ENC,ENC,H,H) fp32
    float* __restrict__ enc_feat)       // (B,ENC,H) fp32
{
    int b  = blockIdx.x >> 5;
    int o0 = (blockIdx.x & 31) * 2;

    __shared__ float encS[ENC * EP];
    for (int idx = threadIdx.x; idx < ENC * EP; idx += 128) encS[idx] = 0.f;
    __syncthreads();
    for (int idx = threadIdx.x; idx < ENC * HH; idx += 128) {
        int i = idx / HH, j = idx - i * HH;
        encS[i * EP + 47 + j] = enc[(b * ENC + i) * HH + j];
    }
    __syncthreads();

    int x = threadIdx.x;
    if (x < HH) {
        float a0 = 0.f, a1 = 0.f;
        for (int i = 0; i < ENC; ++i) {
            // row base: ((o*ENC+i)*HH + 47)*HH floats -> multiple of 96 -> 384B aligned
            const float4* w0 = (const float4*)(attn_w + (size_t)((((o0 + 0) * ENC + i) * HH + 47) * HH));
            const float4* w1 = (const float4*)(attn_w + (size_t)((((o0 + 1) * ENC + i) * HH + 47) * HH));
            const float* er = encS + i * EP + x;
            #pragma unroll 4
            for (int c = 0; c < HH / 4; ++c) {          // 24 chunks of 4 floats
                float e0 = er[4 * c + 0], e1 = er[4 * c + 1];
                float e2 = er[4 * c + 2], e3 = er[4 * c + 3];
                float4 q0 = w0[c], q1 = w1[c];
                a0 += e0 * q0.x + e1 * q0.y + e2 * q0.z + e3 * q0.w;
                a1 += e0 * q1.x + e1 * q1.y + e2 * q1.z + e3 * q1.w;
            }
        }
        float* outr = enc_feat + (b * ENC + o0) * HH + x;
        outr[0 * HH] = a0; outr[1 * HH] = a1;
    }
}

// ---------------------------------------------------------------------------
// attention pass (per-b block, 128 threads). Updates covS += aw in place.
// ---------------------------------------------------------------------------
__device__ void attn_pass(int b, int t,
    const float* __restrict__ enc,
    const float* __restrict__ W_dec, const float* __restrict__ b_dec,
    const float* __restrict__ attn_b,
    const float* __restrict__ cvg_w, const float* __restrict__ cvg_b,
    const float* __restrict__ enc_feat,
    const float* hvec, float* covS, const float* vS,
    float* decS, float* cvgS, float* sS, float* eS, float* awS, float* ctxOut)
{
    if (t < HH) {
        float d = b_dec[t];
        const float* wr = W_dec + t * HH;
        for (int k = 0; k < HH; ++k) d += hvec[k] * wr[k];
        decS[t] = d;
    }
    if (t < ENC) {
        float c = cvg_b[t];
        for (int i = 0; i < ENC; ++i) c += covS[i] * cvg_w[(t * ENC + i) * HH + 47];
        cvgS[t] = c;
    }
    __syncthreads();
    if (t < ENC) {
        float base = attn_b[t] + cvgS[t];
        const float* efr = enc_feat + (b * ENC + t) * HH;
        float s = 0.f;
        for (int x = 0; x < HH; ++x) s += tanhf(efr[x] + decS[x] + base) * vS[x];
        sS[t] = s;
    }
    __syncthreads();
    if (t < ENC) {
        float m = -1e30f;
        for (int j = 0; j < ENC; ++j) m = fmaxf(m, sS[j]);
        eS[t] = expf(sS[t] - m);
    }
    __syncthreads();
    if (t < ENC) {
        float sum = 0.f;
        for (int j = 0; j < ENC; ++j) sum += eS[j];
        float aw = eS[t] / sum;
        awS[t] = aw;
        covS[t] += aw;
    }
    __syncthreads();
    if (t < HH) {
        float c = 0.f;
        for (int o = 0; o < ENC; ++o) c += awS[o] * enc[(b * ENC + o) * HH + t];
        ctxOut[t] = c;
    }
    __syncthreads();
}

// ---------------------------------------------------------------------------
// K1: fused attn1 + GRU + attn2 + pre-output, one block per b. fp32 outputs.
// ---------------------------------------------------------------------------
__global__ __launch_bounds__(128) void k_fused(
    const float* __restrict__ enc, const int* __restrict__ ids,
    const float* __restrict__ hidden, const float* __restrict__ coverage,
    const float* __restrict__ emb,
    const float* __restrict__ W_dec, const float* __restrict__ b_dec,
    const float* __restrict__ attn_b,
    const float* __restrict__ cvg_w, const float* __restrict__ cvg_b,
    const float* __restrict__ vvec,
    const float* __restrict__ W_new, const float* __restrict__ b_new,
    const float* __restrict__ w_ih, const float* __restrict__ w_hh,
    const float* __restrict__ b_ih, const float* __restrict__ b_hh,
    const float* __restrict__ W_pre, const float* __restrict__ b_pre,
    const float* __restrict__ enc_feat, float* __restrict__ oG,
    float* __restrict__ out_hidden, float* __restrict__ out_ctx2,
    float* __restrict__ out_aw2, float* __restrict__ out_cov2)
{
    int b = blockIdx.x, t = threadIdx.x;
    __shared__ float hS[HH], covS[ENC], decS[HH], cvgS[ENC], sS[ENC], eS[ENC],
                     awS[ENC], vS[HH], ctxS[HH], embS[EE], xS[HH], h2S[HH], ctx2S[HH];

    if (t < HH)  { hS[t] = hidden[b * HH + t]; vS[t] = vvec[b * HH + t]; }
    if (t < ENC) covS[t] = coverage[b * ENC + t];
    if (t < EE)  embS[t] = emb[(size_t)ids[b] * EE + t];
    __syncthreads();

    // ---- attention 1 ----
    attn_pass(b, t, enc, W_dec, b_dec, attn_b, cvg_w, cvg_b, enc_feat,
              hS, covS, vS, decS, cvgS, sS, eS, awS, ctxS);

    // ---- x = [emb, ctx1] @ W_new.T + b_new ----
    if (t < HH) {
        float xv = b_new[t];
        const float* wr = W_new + t * (EE + HH);
        for (int k = 0; k < EE; ++k) xv += embS[k] * wr[k];
        for (int k = 0; k < HH; ++k) xv += ctxS[k] * wr[EE + k];
        xS[t] = xv;
    }
    __syncthreads();

    // ---- GRU step (gate order r, z, n) ----
    if (t < HH) {
        float gir = b_ih[t],          ghr = b_hh[t];
        float giz = b_ih[HH + t],     ghz = b_hh[HH + t];
        float gin = b_ih[2 * HH + t], ghn = b_hh[2 * HH + t];
        const float* wir = w_ih + t * HH;
        const float* wiz = w_ih + (HH + t) * HH;
        const float* win = w_ih + (2 * HH + t) * HH;
        const float* whr = w_hh + t * HH;
        const float* whz = w_hh + (HH + t) * HH;
        const float* whn = w_hh + (2 * HH + t) * HH;
        for (int k = 0; k < HH; ++k) {
            float xk = xS[k], hk = hS[k];
            gir += xk * wir[k]; giz += xk * wiz[k]; gin += xk * win[k];
            ghr += hk * whr[k]; ghz += hk * whz[k]; ghn += hk * whn[k];
        }
        float r = 1.f / (1.f + expf(-(gir + ghr)));
        float z = 1.f / (1.f + expf(-(giz + ghz)));
        float n = tanhf(gin + r * ghn);
        float hn = (1.f - z) * n + z * hS[t];
        h2S[t] = hn;
        out_hidden[b * HH + t] = hn;
    }
    __syncthreads();

    // ---- attention 2 (covS now holds cov1) ----
    attn_pass(b, t, enc, W_dec, b_dec, attn_b, cvg_w, cvg_b, enc_feat,
              h2S, covS, vS, decS, cvgS, sS, eS, awS, ctx2S);

    if (t < ENC) {
        out_aw2[b * ENC + t]  = awS[t];
        out_cov2[b * ENC + t] = covS[t];   // cov2 = cov1 + aw2 (updated in pass)
    }
    if (t < HH) {
        out_ctx2[b * HH + t] = ctx2S[t];
        float ov = b_pre[t];
        const float* wr = W_pre + t * (2 * HH);
        for (int k = 0; k < HH; ++k) ov += h2S[k] * wr[k];
        for (int k = 0; k < HH; ++k) ov += ctx2S[k] * wr[HH + k];
        oG[b * HH + t] = tanhf(ov);
    }
}

// ---------------------------------------------------------------------------
// K2: logits[b,v] = o[b,:] @ W_out[v,:] + b_out[v], fp32 directly into d_out
// grid 125 x 256: one vocab row per thread, all 16 batches
// ---------------------------------------------------------------------------
__global__ __launch_bounds__(256) void k_logits(
    const float* __restrict__ oG, const float* __restrict__ W_out,
    const float* __restrict__ b_out, float* __restrict__ logits)
{
    __shared__ __align__(16) float oS[BB * HH];
    for (int i = threadIdx.x; i < BB * HH; i += 256) oS[i] = oG[i];
    __syncthreads();

    int v = blockIdx.x * 256 + threadIdx.x;   // 125*256 == 32000 exactly
    const float4* row = (const float4*)(W_out + (size_t)v * HH);  // 384B-aligned rows
    float acc[BB];
    #pragma unroll
    for (int b = 0; b < BB; ++b) acc[b] = 0.f;

    for (int c = 0; c < HH / 4; ++c) {        // 24 chunks of 4 floats
        float4 q = row[c];
        #pragma unroll
        for (int b = 0; b < BB; ++b) {
            const float4 o0 = *(const float4*)&oS[b * HH + c * 4];
            acc[b] += q.x * o0.x + q.y * o0.y + q.z * o0.z + q.w * o0.w;
        }
    }
    float bo = b_out[v];
    #pragma unroll
    for (int b = 0; b < BB; ++b) logits[b * VV + v] = acc[b] + bo;
}

// ---------------------------------------------------------------------------
// K3: in-place fp32 log_softmax over the logits living in d_out
// ---------------------------------------------------------------------------
__global__ __launch_bounds__(1024) void k_logsoftmax(float* __restrict__ out)
{
    int b = blockIdx.x, t = threadIdx.x;
    float* row = out + b * VV;
    __shared__ float red[1024];

    float m = -1e30f;
    for (int v = t; v < VV; v += 1024) m = fmaxf(m, row[v]);
    red[t] = m; __syncthreads();
    for (int s = 512; s > 0; s >>= 1) {
        if (t < s) red[t] = fmaxf(red[t], red[t + s]);
        __syncthreads();
    }
    m = red[0]; __syncthreads();

    float sum = 0.f;
    for (int v = t; v < VV; v += 1024) sum += expf(row[v] - m);
    red[t] = sum; __syncthreads();
    for (int s = 512; s > 0; s >>= 1) {
        if (t < s) red[t] += red[t + s];
        __syncthreads();
    }
    float logZ = m + logf(red[0]);   // all reads done before writes below

    for (int v = t; v < VV; v += 1024) row[v] = row[v] - logZ;
}

// ---------------------------------------------------------------------------
extern "C" void kernel_launch(void* const* d_in, const int* in_sizes, int n_in,
                              void* d_out, int out_size, void* d_ws, size_t ws_size,
                              hipStream_t stream) {
    const float* enc    = (const float*)d_in[0];
    const int*   ids    = (const int*)d_in[1];
    const float* hidden = (const float*)d_in[2];
    const float* cover  = (const float*)d_in[3];
    const float* emb    = (const float*)d_in[4];
    const float* W_dec  = (const float*)d_in[5];
    const float* b_dec  = (const float*)d_in[6];
    const float* attn_w = (const float*)d_in[7];
    const float* attn_b = (const float*)d_in[8];
    const float* cvg_w  = (const float*)d_in[9];
    const float* cvg_b  = (const float*)d_in[10];
    const float* vvec   = (const float*)d_in[11];
    const float* W_new  = (const float*)d_in[12];
    const float* b_new  = (const float*)d_in[13];
    const float* w_ih   = (const float*)d_in[14];
    const float* w_hh   = (const float*)d_in[15];
    const float* b_ih   = (const float*)d_in[16];
    const float* b_hh   = (const float*)d_in[17];
    const float* W_pre  = (const float*)d_in[18];
    const float* b_pre  = (const float*)d_in[19];
    const float* W_out  = (const float*)d_in[20];
    const float* b_out  = (const float*)d_in[21];

    // ws layout (floats): [0..1536) oG, [1536..99840) enc_feat  (~400 KB)
    float* wsf      = (float*)d_ws;
    float* oG       = wsf;
    float* enc_feat = wsf + BB * HH;

    float* out        = (float*)d_out;
    float* out_logp   = out;               // 512000 (logits computed in place)
    float* out_hidden = out + 512000;      // 1536
    float* out_ctx2   = out + 513536;      // 1536
    float* out_aw2    = out + 515072;      // 1024
    float* out_cov2   = out + 516096;      // 1024

    k_encfeat<<<512, 128, 0, stream>>>(enc, attn_w, enc_feat);
    k_fused<<<16, 128, 0, stream>>>(enc, ids, hidden, cover, emb, W_dec, b_dec,
                                    attn_b, cvg_w, cvg_b, vvec, W_new, b_new,
                                    w_ih, w_hh, b_ih, b_hh, W_pre, b_pre,
                                    enc_feat, oG,
                                    out_hidden, out_ctx2, out_aw2, out_cov2);
    k_logits<<<125, 256, 0, stream>>>(oG, W_out, b_out, out_logp);
    k_logsoftmax<<<16, 1024, 0, stream>>>(out_logp);
}

// Round 5
// 371.297 us; speedup vs baseline: 1.5192x; 1.5192x over previous
//
#include <hip/hip_runtime.h>

#define BB 16
#define ENC 64
#define HH 96
#define EE 128
#define VV 32000

// ---------------------------------------------------------------------------
// K_prep: zero enc_feat accumulator + extract cvg_w[:, :, 0, 47] column.
// ---------------------------------------------------------------------------
__global__ __launch_bounds__(256) void k_prep(
    const float* __restrict__ cvg_w, float* __restrict__ enc_feat,
    float* __restrict__ cvgw47)
{
    int idx = blockIdx.x * 256 + threadIdx.x;
    if (idx < BB * ENC * HH) enc_feat[idx] = 0.f;
    int e = idx - BB * ENC * HH;
    if (e >= 0 && e < ENC * ENC) cvgw47[e] = cvg_w[e * HH + 47];
}

// ---------------------------------------------------------------------------
// K0: enc_feat[b,o,x] += sum_{i in chunk, kw} attn_w[o,i,47,kw] * encpad[b,i,x+kw]
// grid 2048 = b(16) * otile(16; 4 o) * ichunk(8; 8 i), 128 threads (x lane)
// Weights + enc staged in LDS (coalesced); inner loop: LDS broadcasts + FMA.
// ---------------------------------------------------------------------------
__global__ __launch_bounds__(128) void k_encfeat(
    const float* __restrict__ enc,      // (B,ENC,H)
    const float* __restrict__ attn_w,   // (ENC,ENC,H,H)
    float* __restrict__ enc_feat)       // (B,ENC,H) accumulator
{
    int blk = blockIdx.x;
    int b   = blk >> 7;
    int rem = blk & 127;
    int o0  = (rem >> 3) * 4;
    int i0  = (rem & 7) * 8;

    __shared__ float encS[8 * 192];          // 8 padded rows (47 left pad)
    __shared__ __align__(16) float Wb[4 * 8 * 96];  // [o][i][k]

    for (int f = threadIdx.x; f < 8 * 192; f += 128) encS[f] = 0.f;
    __syncthreads();
    for (int f = threadIdx.x; f < 8 * 96; f += 128) {
        int i = f / 96, j = f - i * 96;
        encS[i * 192 + 47 + j] = enc[(size_t)((b * ENC + i0 + i) * 96) + j];
    }
    // stage weights: 3072 floats = 768 float4, coalesced
    for (int f4 = threadIdx.x; f4 < 768; f4 += 128) {
        int f = f4 * 4;
        int o = f / 768;
        int r = f - o * 768;
        int i = r / 96, k = r - i * 96;
        float4 q = *(const float4*)(attn_w +
            ((size_t)((o0 + o) * ENC + (i0 + i)) * 96 + 47) * 96 + k);
        *(float4*)&Wb[f] = q;
    }
    __syncthreads();

    int x = threadIdx.x;
    if (x < 96) {
        float a0 = 0.f, a1 = 0.f, a2 = 0.f, a3 = 0.f;
        for (int i = 0; i < 8; ++i) {
            const float* er = &encS[i * 192 + x];
            const float* w0 = &Wb[0 * 768 + i * 96];
            const float* w1 = &Wb[1 * 768 + i * 96];
            const float* w2 = &Wb[2 * 768 + i * 96];
            const float* w3 = &Wb[3 * 768 + i * 96];
            #pragma unroll 6
            for (int c = 0; c < 24; ++c) {
                float e0 = er[4 * c + 0], e1 = er[4 * c + 1];
                float e2 = er[4 * c + 2], e3 = er[4 * c + 3];
                float4 q0 = *(const float4*)&w0[4 * c];
                float4 q1 = *(const float4*)&w1[4 * c];
                float4 q2 = *(const float4*)&w2[4 * c];
                float4 q3 = *(const float4*)&w3[4 * c];
                a0 += e0 * q0.x + e1 * q0.y + e2 * q0.z + e3 * q0.w;
                a1 += e0 * q1.x + e1 * q1.y + e2 * q1.z + e3 * q1.w;
                a2 += e0 * q2.x + e1 * q2.y + e2 * q2.z + e3 * q2.w;
                a3 += e0 * q3.x + e1 * q3.y + e2 * q3.z + e3 * q3.w;
            }
        }
        float* outr = enc_feat + (size_t)(b * ENC + o0) * 96 + x;
        unsafeAtomicAdd(outr + 0 * 96, a0);
        unsafeAtomicAdd(outr + 1 * 96, a1);
        unsafeAtomicAdd(outr + 2 * 96, a2);
        unsafeAtomicAdd(outr + 3 * 96, a3);
    }
}

// ---------------------------------------------------------------------------
// cooperative matvec: 4 lanes per output row, coalesced float4 loads,
// shuffle reduce. y[j] = bias[j] + W[j,:nk] . xv   for j in [0,nout)
// 256 threads -> 64 groups. nk % 16 == 0. Row byte stride ldw*4 must be 16B-mult.
// ---------------------------------------------------------------------------
__device__ __forceinline__ void matvec4(int g, int q, int nout, int nk,
    const float* __restrict__ W, int ldw, const float* __restrict__ bias,
    const float* __restrict__ xv, float* __restrict__ y)
{
    for (int j = g; j < nout; j += 64) {
        const float* wr = W + (size_t)j * ldw;
        float s = 0.f;
        for (int m = q; m < nk / 4; m += 4) {
            float4 wq = *(const float4*)(wr + 4 * m);
            s += wq.x * xv[4 * m] + wq.y * xv[4 * m + 1]
               + wq.z * xv[4 * m + 2] + wq.w * xv[4 * m + 3];
        }
        s += __shfl_xor(s, 1);
        s += __shfl_xor(s, 2);
        if (q == 0) y[j] = s + bias[j];
    }
}

// ---------------------------------------------------------------------------
// K1: fused attn1 + GRU + attn2 + pre-output, one block (256 thr) per b.
// ---------------------------------------------------------------------------
__global__ __launch_bounds__(256) void k_fused(
    const float* __restrict__ enc, const int* __restrict__ ids,
    const float* __restrict__ hidden, const float* __restrict__ coverage,
    const float* __restrict__ emb,
    const float* __restrict__ W_dec, const float* __restrict__ b_dec,
    const float* __restrict__ attn_b,
    const float* __restrict__ cvgw47, const float* __restrict__ cvg_b,
    const float* __restrict__ vvec,
    const float* __restrict__ W_new, const float* __restrict__ b_new,
    const float* __restrict__ w_ih, const float* __restrict__ w_hh,
    const float* __restrict__ b_ih, const float* __restrict__ b_hh,
    const float* __restrict__ W_pre, const float* __restrict__ b_pre,
    const float* __restrict__ enc_feat, float* __restrict__ oG,
    float* __restrict__ out_hidden, float* __restrict__ out_ctx2,
    float* __restrict__ out_aw2, float* __restrict__ out_cov2)
{
    int b = blockIdx.x, t = threadIdx.x;
    int g = t >> 2, q = t & 3;

    __shared__ __align__(16) float efS[ENC * HH];    // enc_feat slice (reused both passes)
    __shared__ __align__(16) float encS[ENC * HH];   // enc slice
    __shared__ float hS[HH], vS[HH], decS[HH], ctxS[HH], xS[HH], h2S[HH], ctx2S[HH];
    __shared__ float covS[ENC], cvgS[ENC], sS[ENC], awS[ENC];
    __shared__ float embS[EE];
    __shared__ __align__(16) float xcatS[EE + HH];   // 224; reused (192) for [h2;ctx2]
    __shared__ float giS[3 * HH], ghS[3 * HH];

    for (int f = t; f < ENC * HH; f += 256) {
        efS[f]  = enc_feat[(size_t)b * ENC * HH + f];
        encS[f] = enc[(size_t)b * ENC * HH + f];
    }
    if (t < HH) { hS[t] = hidden[b * HH + t]; vS[t] = vvec[b * HH + t]; }
    if (t >= 96 && t < 160) covS[t - 96] = coverage[b * ENC + (t - 96)];
    if (t >= 128 && t < 256) embS[t - 128] = emb[(size_t)ids[b] * EE + (t - 128)];
    __syncthreads();

    // ======== attention pass 1 ========
    matvec4(g, q, HH, HH, W_dec, HH, b_dec, hS, decS);
    matvec4(g, q, ENC, ENC, cvgw47, ENC, cvg_b, covS, cvgS);
    __syncthreads();
    {   // scores: group g = e
        int e = g;
        float base = attn_b[e] + cvgS[e];
        const float* efr = &efS[e * HH];
        float s = 0.f;
        for (int m = q; m < 24; m += 4) {
            #pragma unroll
            for (int u = 0; u < 4; ++u) {
                int xx = 4 * m + u;
                s += tanhf(efr[xx] + decS[xx] + base) * vS[xx];
            }
        }
        s += __shfl_xor(s, 1); s += __shfl_xor(s, 2);
        if (q == 0) sS[e] = s;
    }
    __syncthreads();
    if (t < ENC) {   // softmax over 64 (wave 0)
        float m = -1e30f;
        for (int j = 0; j < ENC; ++j) m = fmaxf(m, sS[j]);
        float sum = 0.f;
        for (int j = 0; j < ENC; ++j) sum += expf(sS[j] - m);
        float aw = expf(sS[t] - m) / sum;
        awS[t] = aw;
        covS[t] += aw;
    }
    __syncthreads();
    if (t < HH) {    // ctx1
        float c = 0.f;
        for (int o = 0; o < ENC; ++o) c += awS[o] * encS[o * HH + t];
        ctxS[t] = c;
        xcatS[EE + t] = c;
    }
    if (t >= 128 && t < 256) xcatS[t - 128] = embS[t - 128];
    __syncthreads();

    // ======== x = W_new @ [emb; ctx1] + b_new ========
    matvec4(g, q, HH, EE + HH, W_new, EE + HH, b_new, xcatS, xS);
    __syncthreads();

    // ======== GRU ========
    matvec4(g, q, 3 * HH, HH, w_ih, HH, b_ih, xS, giS);
    matvec4(g, q, 3 * HH, HH, w_hh, HH, b_hh, hS, ghS);
    __syncthreads();
    if (t < HH) {
        float r = 1.f / (1.f + expf(-(giS[t] + ghS[t])));
        float z = 1.f / (1.f + expf(-(giS[HH + t] + ghS[HH + t])));
        float n = tanhf(giS[2 * HH + t] + r * ghS[2 * HH + t]);
        float hn = (1.f - z) * n + z * hS[t];
        h2S[t] = hn;
        out_hidden[b * HH + t] = hn;
    }
    __syncthreads();

    // ======== attention pass 2 (covS now = cov1) ========
    matvec4(g, q, HH, HH, W_dec, HH, b_dec, h2S, decS);
    matvec4(g, q, ENC, ENC, cvgw47, ENC, cvg_b, covS, cvgS);
    __syncthreads();
    {
        int e = g;
        float base = attn_b[e] + cvgS[e];
        const float* efr = &efS[e * HH];
        float s = 0.f;
        for (int m = q; m < 24; m += 4) {
            #pragma unroll
            for (int u = 0; u < 4; ++u) {
                int xx = 4 * m + u;
                s += tanhf(efr[xx] + decS[xx] + base) * vS[xx];
            }
        }
        s += __shfl_xor(s, 1); s += __shfl_xor(s, 2);
        if (q == 0) sS[e] = s;
    }
    __syncthreads();
    if (t < ENC) {
        float m = -1e30f;
        for (int j = 0; j < ENC; ++j) m = fmaxf(m, sS[j]);
        float sum = 0.f;
        for (int j = 0; j < ENC; ++j) sum += expf(sS[j] - m);
        float aw = expf(sS[t] - m) / sum;
        awS[t] = aw;
        covS[t] += aw;
        out_aw2[b * ENC + t]  = aw;
        out_cov2[b * ENC + t] = covS[t];
    }
    __syncthreads();
    if (t < HH) {    // ctx2 + build [h2; ctx2]
        float c = 0.f;
        for (int o = 0; o < ENC; ++o) c += awS[o] * encS[o * HH + t];
        ctx2S[t] = c;
        out_ctx2[b * HH + t] = c;
        xcatS[t] = h2S[t];
        xcatS[HH + t] = c;
    }
    __syncthreads();

    // ======== o = tanh(W_pre @ [h2; ctx2] + b_pre) ========
    for (int j = g; j < HH; j += 64) {
        const float* wr = W_pre + (size_t)j * (2 * HH);
        float s = 0.f;
        for (int m = q; m < (2 * HH) / 4; m += 4) {
            float4 wq = *(const float4*)(wr + 4 * m);
            s += wq.x * xcatS[4 * m] + wq.y * xcatS[4 * m + 1]
               + wq.z * xcatS[4 * m + 2] + wq.w * xcatS[4 * m + 3];
        }
        s += __shfl_xor(s, 1); s += __shfl_xor(s, 2);
        if (q == 0) oG[b * HH + j] = tanhf(s + b_pre[j]);
    }
}

// ---------------------------------------------------------------------------
// K2: logits[b,v] = o[b,:] @ W_out[v,:] + b_out[v], fp32 directly into d_out
// ---------------------------------------------------------------------------
__global__ __launch_bounds__(256) void k_logits(
    const float* __restrict__ oG, const float* __restrict__ W_out,
    const float* __restrict__ b_out, float* __restrict__ logits)
{
    __shared__ __align__(16) float oS[BB * HH];
    for (int i = threadIdx.x; i < BB * HH; i += 256) oS[i] = oG[i];
    __syncthreads();

    int v = blockIdx.x * 256 + threadIdx.x;   // 125*256 == 32000
    const float4* row = (const float4*)(W_out + (size_t)v * HH);
    float acc[BB];
    #pragma unroll
    for (int b = 0; b < BB; ++b) acc[b] = 0.f;

    for (int c = 0; c < HH / 4; ++c) {
        float4 qv = row[c];
        #pragma unroll
        for (int b = 0; b < BB; ++b) {
            const float4 o0 = *(const float4*)&oS[b * HH + c * 4];
            acc[b] += qv.x * o0.x + qv.y * o0.y + qv.z * o0.z + qv.w * o0.w;
        }
    }
    float bo = b_out[v];
    #pragma unroll
    for (int b = 0; b < BB; ++b) logits[b * VV + v] = acc[b] + bo;
}

// ---------------------------------------------------------------------------
// K3: in-place fp32 log_softmax over logits in d_out
// ---------------------------------------------------------------------------
__global__ __launch_bounds__(1024) void k_logsoftmax(float* __restrict__ out)
{
    int b = blockIdx.x, t = threadIdx.x;
    float* row = out + (size_t)b * VV;
    __shared__ float red[1024];

    float m = -1e30f;
    for (int v = t; v < VV; v += 1024) m = fmaxf(m, row[v]);
    red[t] = m; __syncthreads();
    for (int s = 512; s > 0; s >>= 1) {
        if (t < s) red[t] = fmaxf(red[t], red[t + s]);
        __syncthreads();
    }
    m = red[0]; __syncthreads();

    float sum = 0.f;
    for (int v = t; v < VV; v += 1024) sum += expf(row[v] - m);
    red[t] = sum; __syncthreads();
    for (int s = 512; s > 0; s >>= 1) {
        if (t < s) red[t] += red[t + s];
        __syncthreads();
    }
    float logZ = m + logf(red[0]);

    for (int v = t; v < VV; v += 1024) row[v] = row[v] - logZ;
}

// ---------------------------------------------------------------------------
extern "C" void kernel_launch(void* const* d_in, const int* in_sizes, int n_in,
                              void* d_out, int out_size, void* d_ws, size_t ws_size,
                              hipStream_t stream) {
    const float* enc    = (const float*)d_in[0];
    const int*   ids    = (const int*)d_in[1];
    const float* hidden = (const float*)d_in[2];
    const float* cover  = (const float*)d_in[3];
    const float* emb    = (const float*)d_in[4];
    const float* W_dec  = (const float*)d_in[5];
    const float* b_dec  = (const float*)d_in[6];
    const float* attn_w = (const float*)d_in[7];
    const float* attn_b = (const float*)d_in[8];
    const float* cvg_w  = (const float*)d_in[9];
    const float* cvg_b  = (const float*)d_in[10];
    const float* vvec   = (const float*)d_in[11];
    const float* W_new  = (const float*)d_in[12];
    const float* b_new  = (const float*)d_in[13];
    const float* w_ih   = (const float*)d_in[14];
    const float* w_hh   = (const float*)d_in[15];
    const float* b_ih   = (const float*)d_in[16];
    const float* b_hh   = (const float*)d_in[17];
    const float* W_pre  = (const float*)d_in[18];
    const float* b_pre  = (const float*)d_in[19];
    const float* W_out  = (const float*)d_in[20];
    const float* b_out  = (const float*)d_in[21];

    // ws (floats): [0..1536) oG | [1536..5632) cvgw47 | [5632..103936) enc_feat
    float* wsf      = (float*)d_ws;
    float* oG       = wsf;
    float* cvgw47   = wsf + 1536;
    float* enc_feat = wsf + 5632;

    float* out        = (float*)d_out;
    float* out_logp   = out;               // 512000 (logits in place)
    float* out_hidden = out + 512000;
    float* out_ctx2   = out + 513536;
    float* out_aw2    = out + 515072;
    float* out_cov2   = out + 516096;

    k_prep<<<400, 256, 0, stream>>>(cvg_w, enc_feat, cvgw47);
    k_encfeat<<<2048, 128, 0, stream>>>(enc, attn_w, enc_feat);
    k_fused<<<16, 256, 0, stream>>>(enc, ids, hidden, cover, emb, W_dec, b_dec,
                                    attn_b, cvgw47, cvg_b, vvec, W_new, b_new,
                                    w_ih, w_hh, b_ih, b_hh, W_pre, b_pre,
                                    enc_feat, oG,
                                    out_hidden, out_ctx2, out_aw2, out_cov2);
    k_logits<<<125, 256, 0, stream>>>(oG, W_out, b_out, out_logp);
    k_logsoftmax<<<16, 1024, 0, stream>>>(out_logp);
}

// Round 6
// 360.785 us; speedup vs baseline: 1.5635x; 1.0291x over previous
//
#include <hip/hip_runtime.h>

#define BB 16
#define ENC 64
#define HH 96
#define EE 128
#define VV 32000

__device__ __forceinline__ float tanh_fast(float x) {
    // exact at saturation: exp(2x)->inf => 1; ->0 => -1
    float e = __expf(2.f * x);
    return 1.f - 2.f / (e + 1.f);
}
__device__ __forceinline__ float sigmoid_fast(float x) {
    return 1.f / (1.f + __expf(-x));
}

// ---------------------------------------------------------------------------
// K0: partial enc_feat. part[ic][b][o][x] = sum_{i in chunk, kw} attn_w[o,i,47,kw]
//     * encpad[b,i,x+kw].  (conv kh collapses to 47: input height 1, pad(47,48))
// grid 1024 = b(16) * otile(8; 8 o) * ichunk(8; 8 i), 128 threads (x lane)
// Blocks with b==0,ot==0 also extract cvg_w[:,:,0,47] -> cvgw47.
// ---------------------------------------------------------------------------
__global__ __launch_bounds__(128) void k_encfeat(
    const float* __restrict__ enc,      // (B,ENC,H)
    const float* __restrict__ attn_w,   // (ENC,ENC,H,H)
    const float* __restrict__ cvg_w,    // (ENC,ENC,1,H)
    float* __restrict__ part,           // (8,B,ENC,H) partial sums
    float* __restrict__ cvgw47)         // (ENC,ENC)
{
    int blk = blockIdx.x;
    int b   = blk >> 6;
    int ot  = (blk >> 3) & 7;
    int ic  = blk & 7;
    int o0  = ot * 8;
    int i0  = ic * 8;
    int t   = threadIdx.x;

    __shared__ float encS[8 * 192];                  // 8 padded rows
    __shared__ __align__(16) float Wb[8 * 8 * 96];   // [o][i][k]

    for (int f = t; f < 8 * 192; f += 128) encS[f] = 0.f;
    __syncthreads();
    for (int f = t; f < 8 * 96; f += 128) {
        int i = f / 96, j = f - i * 96;
        encS[i * 192 + 47 + j] = enc[(size_t)((b * ENC + i0 + i) * 96) + j];
    }
    // stage weights: 6144 floats = 1536 float4, coalesced (12 per thread)
    for (int f4 = t; f4 < 1536; f4 += 128) {
        int o = f4 / 192;
        int r = f4 - o * 192;
        int i = r / 24, kq = r - i * 24;
        float4 q = *(const float4*)(attn_w +
            (size_t)((o0 + o) * ENC + (i0 + i)) * (96 * 96) + 47 * 96 + 4 * kq);
        *(float4*)&Wb[(o * 8 + i) * 96 + 4 * kq] = q;
    }
    // side job: cvgw47 extraction (8 blocks cover 4096 elems)
    if (b == 0 && ot == 0) {
        #pragma unroll
        for (int j = 0; j < 4; ++j) {
            int e = ic * 512 + j * 128 + t;
            cvgw47[e] = cvg_w[(size_t)e * 96 + 47];
        }
    }
    __syncthreads();

    int x = t;
    if (x < 96) {
        float acc[8];
        #pragma unroll
        for (int o = 0; o < 8; ++o) acc[o] = 0.f;
        for (int i = 0; i < 8; ++i) {
            const float* er = &encS[i * 192 + x];
            const float* wb = &Wb[i * 96];
            #pragma unroll 4
            for (int c = 0; c < 24; ++c) {
                float e0 = er[4 * c + 0], e1 = er[4 * c + 1];
                float e2 = er[4 * c + 2], e3 = er[4 * c + 3];
                #pragma unroll
                for (int o = 0; o < 8; ++o) {
                    float4 q = *(const float4*)&wb[o * (8 * 96) + 4 * c];
                    acc[o] += e0 * q.x + e1 * q.y + e2 * q.z + e3 * q.w;
                }
            }
        }
        float* outr = part + ((size_t)(ic * 16 + b) * 64 + o0) * 96 + x;
        #pragma unroll
        for (int o = 0; o < 8; ++o) outr[o * 96] = acc[o];
    }
}

// ---------------------------------------------------------------------------
// cooperative matvec: 4 lanes per output row, float4 loads, shuffle reduce.
// ---------------------------------------------------------------------------
__device__ __forceinline__ void matvec4(int g, int q, int nout, int nk,
    const float* __restrict__ W, int ldw, const float* __restrict__ bias,
    const float* __restrict__ xv, float* __restrict__ y)
{
    for (int j = g; j < nout; j += 64) {
        const float* wr = W + (size_t)j * ldw;
        float s = 0.f;
        for (int m = q; m < nk / 4; m += 4) {
            float4 wq = *(const float4*)(wr + 4 * m);
            s += wq.x * xv[4 * m] + wq.y * xv[4 * m + 1]
               + wq.z * xv[4 * m + 2] + wq.w * xv[4 * m + 3];
        }
        s += __shfl_xor(s, 1);
        s += __shfl_xor(s, 2);
        if (q == 0) y[j] = s + bias[j];
    }
}

// ---------------------------------------------------------------------------
// K1: fused attn1 + GRU + attn2 + pre-output, one block (256 thr) per b.
// ---------------------------------------------------------------------------
__global__ __launch_bounds__(256) void k_fused(
    const float* __restrict__ enc, const int* __restrict__ ids,
    const float* __restrict__ hidden, const float* __restrict__ coverage,
    const float* __restrict__ emb,
    const float* __restrict__ W_dec, const float* __restrict__ b_dec,
    const float* __restrict__ attn_b,
    const float* __restrict__ cvgw47, const float* __restrict__ cvg_b,
    const float* __restrict__ vvec,
    const float* __restrict__ W_new, const float* __restrict__ b_new,
    const float* __restrict__ w_ih, const float* __restrict__ w_hh,
    const float* __restrict__ b_ih, const float* __restrict__ b_hh,
    const float* __restrict__ W_pre, const float* __restrict__ b_pre,
    const float* __restrict__ part, float* __restrict__ oG,
    float* __restrict__ out_hidden, float* __restrict__ out_ctx2,
    float* __restrict__ out_aw2, float* __restrict__ out_cov2)
{
    int b = blockIdx.x, t = threadIdx.x;
    int g = t >> 2, q = t & 3;

    __shared__ __align__(16) float efS[ENC * HH];    // summed enc_feat slice
    __shared__ __align__(16) float encS[ENC * HH];   // enc slice
    __shared__ float hS[HH], vS[HH], decS[HH], ctxS[HH], xS[HH], h2S[HH], ctx2S[HH];
    __shared__ float covS[ENC], cvgS[ENC], sS[ENC], awS[ENC];
    __shared__ float embS[EE];
    __shared__ __align__(16) float xcatS[EE + HH];
    __shared__ float giS[3 * HH], ghS[3 * HH];

    for (int f = t; f < ENC * HH; f += 256) {
        float s = 0.f;
        #pragma unroll
        for (int ic = 0; ic < 8; ++ic)
            s += part[(size_t)(ic * 16 + b) * (ENC * HH) + f];
        efS[f]  = s;
        encS[f] = enc[(size_t)b * ENC * HH + f];
    }
    if (t < HH) { hS[t] = hidden[b * HH + t]; vS[t] = vvec[b * HH + t]; }
    if (t >= 96 && t < 160) covS[t - 96] = coverage[b * ENC + (t - 96)];
    if (t >= 128 && t < 256) embS[t - 128] = emb[(size_t)ids[b] * EE + (t - 128)];
    __syncthreads();

    // ======== attention pass 1 ========
    matvec4(g, q, HH, HH, W_dec, HH, b_dec, hS, decS);
    matvec4(g, q, ENC, ENC, cvgw47, ENC, cvg_b, covS, cvgS);
    __syncthreads();
    {
        int e = g;
        float base = attn_b[e] + cvgS[e];
        const float* efr = &efS[e * HH];
        float s = 0.f;
        for (int m = q; m < 24; m += 4) {
            #pragma unroll
            for (int u = 0; u < 4; ++u) {
                int xx = 4 * m + u;
                s += tanh_fast(efr[xx] + decS[xx] + base) * vS[xx];
            }
        }
        s += __shfl_xor(s, 1); s += __shfl_xor(s, 2);
        if (q == 0) sS[e] = s;
    }
    __syncthreads();
    if (t < ENC) {
        float m = -1e30f;
        for (int j = 0; j < ENC; ++j) m = fmaxf(m, sS[j]);
        float sum = 0.f;
        for (int j = 0; j < ENC; ++j) sum += __expf(sS[j] - m);
        float aw = __expf(sS[t] - m) / sum;
        awS[t] = aw;
        covS[t] += aw;
    }
    __syncthreads();
    if (t < HH) {
        float c = 0.f;
        for (int o = 0; o < ENC; ++o) c += awS[o] * encS[o * HH + t];
        ctxS[t] = c;
        xcatS[EE + t] = c;
    }
    if (t >= 128 && t < 256) xcatS[t - 128] = embS[t - 128];
    __syncthreads();

    // ======== x = W_new @ [emb; ctx1] + b_new ========
    matvec4(g, q, HH, EE + HH, W_new, EE + HH, b_new, xcatS, xS);
    __syncthreads();

    // ======== GRU (gate order r, z, n) ========
    matvec4(g, q, 3 * HH, HH, w_ih, HH, b_ih, xS, giS);
    matvec4(g, q, 3 * HH, HH, w_hh, HH, b_hh, hS, ghS);
    __syncthreads();
    if (t < HH) {
        float r = sigmoid_fast(giS[t] + ghS[t]);
        float z = sigmoid_fast(giS[HH + t] + ghS[HH + t]);
        float n = tanh_fast(giS[2 * HH + t] + r * ghS[2 * HH + t]);
        float hn = (1.f - z) * n + z * hS[t];
        h2S[t] = hn;
        out_hidden[b * HH + t] = hn;
    }
    __syncthreads();

    // ======== attention pass 2 (covS now = cov1) ========
    matvec4(g, q, HH, HH, W_dec, HH, b_dec, h2S, decS);
    matvec4(g, q, ENC, ENC, cvgw47, ENC, cvg_b, covS, cvgS);
    __syncthreads();
    {
        int e = g;
        float base = attn_b[e] + cvgS[e];
        const float* efr = &efS[e * HH];
        float s = 0.f;
        for (int m = q; m < 24; m += 4) {
            #pragma unroll
            for (int u = 0; u < 4; ++u) {
                int xx = 4 * m + u;
                s += tanh_fast(efr[xx] + decS[xx] + base) * vS[xx];
            }
        }
        s += __shfl_xor(s, 1); s += __shfl_xor(s, 2);
        if (q == 0) sS[e] = s;
    }
    __syncthreads();
    if (t < ENC) {
        float m = -1e30f;
        for (int j = 0; j < ENC; ++j) m = fmaxf(m, sS[j]);
        float sum = 0.f;
        for (int j = 0; j < ENC; ++j) sum += __expf(sS[j] - m);
        float aw = __expf(sS[t] - m) / sum;
        awS[t] = aw;
        covS[t] += aw;
        out_aw2[b * ENC + t]  = aw;
        out_cov2[b * ENC + t] = covS[t];
    }
    __syncthreads();
    if (t < HH) {
        float c = 0.f;
        for (int o = 0; o < ENC; ++o) c += awS[o] * encS[o * HH + t];
        ctx2S[t] = c;
        out_ctx2[b * HH + t] = c;
        xcatS[t] = h2S[t];
        xcatS[HH + t] = c;
    }
    __syncthreads();

    // ======== o = tanh(W_pre @ [h2; ctx2] + b_pre) ========
    for (int j = g; j < HH; j += 64) {
        const float* wr = W_pre + (size_t)j * (2 * HH);
        float s = 0.f;
        for (int m = q; m < (2 * HH) / 4; m += 4) {
            float4 wq = *(const float4*)(wr + 4 * m);
            s += wq.x * xcatS[4 * m] + wq.y * xcatS[4 * m + 1]
               + wq.z * xcatS[4 * m + 2] + wq.w * xcatS[4 * m + 3];
        }
        s += __shfl_xor(s, 1); s += __shfl_xor(s, 2);
        if (q == 0) oG[b * HH + j] = tanh_fast(s + b_pre[j]);
    }
}

// ---------------------------------------------------------------------------
// K2: logits[b,v] = o[b,:] @ W_out[v,:] + b_out[v], fp32 directly into d_out
// ---------------------------------------------------------------------------
__global__ __launch_bounds__(256) void k_logits(
    const float* __restrict__ oG, const float* __restrict__ W_out,
    const float* __restrict__ b_out, float* __restrict__ logits)
{
    __shared__ __align__(16) float oS[BB * HH];
    for (int i = threadIdx.x; i < BB * HH; i += 256) oS[i] = oG[i];
    __syncthreads();

    int v = blockIdx.x * 256 + threadIdx.x;   // 125*256 == 32000
    const float4* row = (const float4*)(W_out + (size_t)v * HH);
    float acc[BB];
    #pragma unroll
    for (int b = 0; b < BB; ++b) acc[b] = 0.f;

    #pragma unroll 6
    for (int c = 0; c < HH / 4; ++c) {
        float4 qv = row[c];
        #pragma unroll
        for (int b = 0; b < BB; ++b) {
            const float4 o0 = *(const float4*)&oS[b * HH + c * 4];
            acc[b] += qv.x * o0.x + qv.y * o0.y + qv.z * o0.z + qv.w * o0.w;
        }
    }
    float bo = b_out[v];
    #pragma unroll
    for (int b = 0; b < BB; ++b) logits[b * VV + v] = acc[b] + bo;
}

// ---------------------------------------------------------------------------
// K3: in-place fp32 log_softmax (4-way unrolled reductions for MLP)
// ---------------------------------------------------------------------------
__global__ __launch_bounds__(1024) void k_logsoftmax(float* __restrict__ out)
{
    int b = blockIdx.x, t = threadIdx.x;
    float* row = out + (size_t)b * VV;
    __shared__ float red[1024];

    float m0 = -1e30f, m1 = -1e30f, m2 = -1e30f, m3 = -1e30f;
    int v = t;
    for (; v + 3072 < VV; v += 4096) {
        m0 = fmaxf(m0, row[v]);
        m1 = fmaxf(m1, row[v + 1024]);
        m2 = fmaxf(m2, row[v + 2048]);
        m3 = fmaxf(m3, row[v + 3072]);
    }
    for (; v < VV; v += 1024) m0 = fmaxf(m0, row[v]);
    red[t] = fmaxf(fmaxf(m0, m1), fmaxf(m2, m3));
    __syncthreads();
    for (int s = 512; s > 0; s >>= 1) {
        if (t < s) red[t] = fmaxf(red[t], red[t + s]);
        __syncthreads();
    }
    float m = red[0]; __syncthreads();

    float s0 = 0.f, s1 = 0.f, s2 = 0.f, s3 = 0.f;
    v = t;
    for (; v + 3072 < VV; v += 4096) {
        s0 += __expf(row[v] - m);
        s1 += __expf(row[v + 1024] - m);
        s2 += __expf(row[v + 2048] - m);
        s3 += __expf(row[v + 3072] - m);
    }
    for (; v < VV; v += 1024) s0 += __expf(row[v] - m);
    red[t] = (s0 + s1) + (s2 + s3);
    __syncthreads();
    for (int s = 512; s > 0; s >>= 1) {
        if (t < s) red[t] += red[t + s];
        __syncthreads();
    }
    float logZ = m + logf(red[0]);

    for (v = t; v < VV; v += 1024) row[v] = row[v] - logZ;
}

// ---------------------------------------------------------------------------
extern "C" void kernel_launch(void* const* d_in, const int* in_sizes, int n_in,
                              void* d_out, int out_size, void* d_ws, size_t ws_size,
                              hipStream_t stream) {
    const float* enc    = (const float*)d_in[0];
    const int*   ids    = (const int*)d_in[1];
    const float* hidden = (const float*)d_in[2];
    const float* cover  = (const float*)d_in[3];
    const float* emb    = (const float*)d_in[4];
    const float* W_dec  = (const float*)d_in[5];
    const float* b_dec  = (const float*)d_in[6];
    const float* attn_w = (const float*)d_in[7];
    const float* attn_b = (const float*)d_in[8];
    const float* cvg_w  = (const float*)d_in[9];
    const float* cvg_b  = (const float*)d_in[10];
    const float* vvec   = (const float*)d_in[11];
    const float* W_new  = (const float*)d_in[12];
    const float* b_new  = (const float*)d_in[13];
    const float* w_ih   = (const float*)d_in[14];
    const float* w_hh   = (const float*)d_in[15];
    const float* b_ih   = (const float*)d_in[16];
    const float* b_hh   = (const float*)d_in[17];
    const float* W_pre  = (const float*)d_in[18];
    const float* b_pre  = (const float*)d_in[19];
    const float* W_out  = (const float*)d_in[20];
    const float* b_out  = (const float*)d_in[21];

    // ws (floats): [0..1536) oG | [1536..5632) cvgw47 | [5632..792064) part
    float* wsf    = (float*)d_ws;
    float* oG     = wsf;
    float* cvgw47 = wsf + 1536;
    float* part   = wsf + 5632;        // 8*16*64*96 = 786432 floats (~3 MB)

    float* out        = (float*)d_out;
    float* out_logp   = out;               // 512000 (logits in place)
    float* out_hidden = out + 512000;
    float* out_ctx2   = out + 513536;
    float* out_aw2    = out + 515072;
    float* out_cov2   = out + 516096;

    k_encfeat<<<1024, 128, 0, stream>>>(enc, attn_w, cvg_w, part, cvgw47);
    k_fused<<<16, 256, 0, stream>>>(enc, ids, hidden, cover, emb, W_dec, b_dec,
                                    attn_b, cvgw47, cvg_b, vvec, W_new, b_new,
                                    w_ih, w_hh, b_ih, b_hh, W_pre, b_pre,
                                    part, oG,
                                    out_hidden, out_ctx2, out_aw2, out_cov2);
    k_logits<<<125, 256, 0, stream>>>(oG, W_out, b_out, out_logp);
    k_logsoftmax<<<16, 1024, 0, stream>>>(out_logp);
}